// Round 8
// baseline (292.696 us; speedup 1.0000x reference)
//
#include <hip/hip_runtime.h>

#define T_DIM 64
#define N_DIM 2000
#define C_DIM 64
#define E_DIM 32000
#define ROWS (T_DIM * N_DIM)   // 128000
#define BN_EPS 1e-5f

typedef short s8v __attribute__((ext_vector_type(8)));
typedef float f4v __attribute__((ext_vector_type(4)));

__device__ __forceinline__ ushort f2b(float f) {
    unsigned u = __float_as_uint(f);
    unsigned r = u + 0x7FFF + ((u >> 16) & 1);
    return (ushort)(r >> 16);
}

// ---------------- prep ----------------

// blocks 0..124: degree atomics. 125..172: Wc1[k1][ik][c]. block 173: buc[c]
__global__ void k_pre1(const int* __restrict__ ei, const float* __restrict__ c1w,
                       const float* __restrict__ gw, const float* __restrict__ c1b,
                       int* __restrict__ deg, float* __restrict__ Wc1,
                       float* __restrict__ bucg) {
    if (blockIdx.x < 125) {
        int e = blockIdx.x * 256 + threadIdx.x;          // < 32000 exactly
        atomicAdd(&deg[ei[E_DIM + e]], 1);
    } else if (blockIdx.x < 173) {
        int gid = (blockIdx.x - 125) * 256 + threadIdx.x; // < 12288 exactly
        int k1 = gid >> 12, ik = (gid >> 6) & 63, c = gid & 63;
        float s = 0.f;
        for (int j = 0; j < 64; ++j)
            s += c1w[j * 192 + ik * 3 + k1] * gw[j * 64 + c];
        Wc1[gid] = s;
    } else {
        int c = threadIdx.x;
        if (c < 64) {
            float s = 0.f;
            #pragma unroll 8
            for (int j = 0; j < 64; ++j) s += c1b[j] * gw[j * 64 + c];
            bucg[c] = s;
        }
    }
}

// merged pre2+pre3: blocks 0..28 compose weights (1024 thr each);
// block 29: dinv + scan + self-edges + cursor + a_n + bnstats zero.
__global__ __launch_bounds__(1024) void k_pre23(
    const int* __restrict__ deg, const float* __restrict__ Wc1,
    const float* __restrict__ c2w, const float* __restrict__ gb,
    const float* __restrict__ c2b, const float* __restrict__ bucg,
    float* __restrict__ dinv_g, int* __restrict__ offs, int* __restrict__ cursor,
    int2* __restrict__ edat, float* __restrict__ a_arr, float* __restrict__ bnstats,
    ushort* __restrict__ W12f, float* __restrict__ uvec, float* __restrict__ vvec) {
    int tid = threadIdx.x;
    if (blockIdx.x < 29) {
        int gid = blockIdx.x * 1024 + tid;
        if (gid < 320 * 64) {
            // main composed taps j=0..4: W12[j][ik][o] = sum_{k1+k2=j} Wc1[k1][ik][:]·c2w[o][:][k2]
            int kk = gid >> 6, o = gid & 63;
            int j = kk >> 6, ik = kk & 63;
            float sum = 0.f;
            #pragma unroll
            for (int k1 = 0; k1 < 3; ++k1) {
                int k2 = j - k1;
                if (k2 >= 0 && k2 <= 2) {
                    for (int c = 0; c < 64; ++c)
                        sum += Wc1[k1 * 4096 + ik * 64 + c] * c2w[o * 192 + c * 3 + k2];
                }
            }
            int s = kk >> 5, q = (kk >> 3) & 3, jj = kk & 7, cc = o >> 4, m = o & 15;
            W12f[(((s * 4 + cc) * 64) + q * 16 + m) * 8 + jj] = f2b(sum);
        } else if (gid < 320 * 64 + 8192) {
            // tap-2 boundary variants: t=0 excludes (k1=2,k2=0); t=63 excludes (k1=0,k2=2)
            int idx = gid - 320 * 64;
            int var = idx >> 12;
            int ik = (idx >> 6) & 63, o = idx & 63;
            float sum = 0.f;
            for (int c = 0; c < 64; ++c) {
                float acc = Wc1[1 * 4096 + ik * 64 + c] * c2w[o * 192 + c * 3 + 1];
                acc += (var == 0)
                    ? Wc1[0 * 4096 + ik * 64 + c] * c2w[o * 192 + c * 3 + 2]
                    : Wc1[2 * 4096 + ik * 64 + c] * c2w[o * 192 + c * 3 + 0];
                sum += acc;
            }
            int kk = 128 + ik;
            int s = kk >> 5, q = (kk >> 3) & 3, jj = kk & 7, cc = o >> 4, m = o & 15;
            int flat = (((s * 4 + cc) * 64) + q * 16 + m) * 8 + jj;   // in [8192,12288)
            W12f[flat - 8192 + 20480 + var * 4096] = f2b(sum);
        } else if (gid < 320 * 64 + 8192 + 192) {
            // rank-1 bias tables (buc precomputed in k_pre1 — was the 61 µs tail)
            int idx = gid - 320 * 64 - 8192;
            int cs = idx >> 6, o = idx & 63;
            float uu = 0.f, vv = 0.f;
            for (int c = 0; c < 64; ++c) {
                float wsum = c2w[o * 192 + c * 3 + 1];
                if (cs != 0) wsum += c2w[o * 192 + c * 3 + 0];
                if (cs != 2) wsum += c2w[o * 192 + c * 3 + 2];
                uu += bucg[c] * wsum;
                vv += gb[c] * wsum;
            }
            uvec[cs * 64 + o] = uu;
            vvec[cs * 64 + o] = vv + c2b[o];
        }
    } else {
        __shared__ int sa[2048], sbuf[2048];
        __shared__ float sdinv[2048];
        if (tid < 128) bnstats[tid] = 0.f;
        for (int i = tid; i < 2048; i += 1024) {
            int d = (i < N_DIM) ? deg[i] : 0;
            sa[i] = (i < N_DIM) ? (d + 1) : 0;
            float dv = (i < N_DIM) ? rsqrtf((float)(d + 1)) : 0.f;
            sdinv[i] = dv;
            if (i < N_DIM) dinv_g[i] = dv;
        }
        __syncthreads();
        int* s = sa; int* d = sbuf;
        for (int off = 1; off < 2048; off <<= 1) {
            for (int i = tid; i < 2048; i += 1024)
                d[i] = s[i] + ((i >= off) ? s[i - off] : 0);
            __syncthreads();
            int* t = s; s = d; d = t;
        }
        for (int i = tid; i < 2048; i += 1024) {
            if (i <= N_DIM) offs[i] = (i == 0) ? 0 : s[i - 1];
            if (i < N_DIM) {
                int off = (i == 0) ? 0 : s[i - 1];
                float dv = sdinv[i];
                edat[off] = make_int2(i, __float_as_int(dv * dv));
                cursor[i] = 1;
                a_arr[i] = dv * dv;
            }
        }
    }
}

__global__ void k_fill(const int* __restrict__ ei, const int* __restrict__ offs,
                       const float* __restrict__ dinv, int* __restrict__ cursor,
                       int2* __restrict__ edat, float* __restrict__ a_arr) {
    int e = blockIdx.x * 256 + threadIdx.x;              // < 32000 exactly
    int s = ei[e];
    int d = ei[E_DIM + e];
    int p = atomicAdd(&cursor[d], 1);
    float w = dinv[s] * dinv[d];
    edat[offs[d] + p] = make_int2(s, __float_as_int(w));
    atomicAdd(&a_arr[d], w);
}

// ---------------- Agg(x): CSR gather, XCD-swizzled (8 contiguous t per XCD) ----------------
__global__ __launch_bounds__(256) void k_gather(
    const float* __restrict__ x, const int* __restrict__ offs,
    const int2* __restrict__ edat, ushort* __restrict__ xg) {
    // blockIdx & 7 = XCD (round-robin dispatch); each XCD owns t in [xcd*8, xcd*8+8)
    int xcd = blockIdx.x & 7;
    int bi = blockIdx.x >> 3;          // 0..3999
    int t = xcd * 8 + bi / 500;
    int nb = bi - (bi / 500) * 500;    // 0..499
    int lane = threadIdx.x & 63;
    int n = nb * 4 + (threadIdx.x >> 6);
    int unit = t * N_DIM + n;
    int g = lane >> 3;            // edge slot 0..7
    int c8 = (lane & 7) * 8;      // channel base
    int beg = offs[n], end = offs[n + 1];
    const float* base = x + (size_t)t * N_DIM * 64 + c8;

    float a[8] = {0.f, 0.f, 0.f, 0.f, 0.f, 0.f, 0.f, 0.f};
    int j = beg + g;
    for (; j + 8 < end; j += 16) {
        int2 e1 = edat[j];
        int2 e2 = edat[j + 8];
        const float* p1 = base + (size_t)e1.x * 64;
        const float* p2 = base + (size_t)e2.x * 64;
        float4 v0 = *(const float4*)p1;
        float4 v1 = *(const float4*)(p1 + 4);
        float4 u0 = *(const float4*)p2;
        float4 u1 = *(const float4*)(p2 + 4);
        float w1 = __int_as_float(e1.y), w2 = __int_as_float(e2.y);
        a[0] += w1 * v0.x + w2 * u0.x; a[1] += w1 * v0.y + w2 * u0.y;
        a[2] += w1 * v0.z + w2 * u0.z; a[3] += w1 * v0.w + w2 * u0.w;
        a[4] += w1 * v1.x + w2 * u1.x; a[5] += w1 * v1.y + w2 * u1.y;
        a[6] += w1 * v1.z + w2 * u1.z; a[7] += w1 * v1.w + w2 * u1.w;
    }
    if (j < end) {
        int2 e = edat[j];
        float w = __int_as_float(e.y);
        const float* p = base + (size_t)e.x * 64;
        float4 v0 = *(const float4*)p;
        float4 v1 = *(const float4*)(p + 4);
        a[0] += w * v0.x; a[1] += w * v0.y; a[2] += w * v0.z; a[3] += w * v0.w;
        a[4] += w * v1.x; a[5] += w * v1.y; a[6] += w * v1.z; a[7] += w * v1.w;
    }
    #pragma unroll
    for (int d = 8; d <= 32; d <<= 1)
        #pragma unroll
        for (int i = 0; i < 8; ++i) a[i] += __shfl_xor(a[i], d);

    if (g == 0) {
        s8v pk;
        #pragma unroll
        for (int i = 0; i < 8; ++i) pk[i] = (short)f2b(a[i]);
        *(s8v*)&xg[(size_t)unit * 64 + c8] = pk;
    }
}

// ---------------- fused K=5 conv GEMM: W in LDS, 2 strips/wave, XCD-swizzled ----------------
__global__ __launch_bounds__(256) void k_conv(
    const ushort* __restrict__ xg, const ushort* __restrict__ Wf,
    const float* __restrict__ uvec, const float* __restrict__ vvec,
    const float* __restrict__ a_arr, float* __restrict__ out,
    float* __restrict__ bnstats) {
    __shared__ __align__(16) ushort Wl[20480];   // 40 KB; reused as sb after MFMA
    int tid = threadIdx.x;
    #pragma unroll
    for (int o = 0; o < 10; ++o) {
        int idx = tid + o * 256;
        *(s8v*)&Wl[idx * 8] = *(const s8v*)&Wf[idx * 8];
    }
    __syncthreads();

    int wv = tid >> 6, lane = tid & 63;
    int m = lane & 15, q = lane >> 4;
    // XCD swizzle: xcd = blk & 7 owns strips [xcd*1000, (xcd+1)*1000) == 8 contiguous t
    int strip0 = (blockIdx.x & 7) * 1000 + (blockIdx.x >> 3) * 8 + wv * 2;
    int t0 = strip0 / 125;
    int t1 = (strip0 + 1) / 125;

    f4v acc[2][4];
    #pragma unroll
    for (int st = 0; st < 2; ++st)
        #pragma unroll
        for (int c = 0; c < 4; ++c) acc[st][c] = (f4v){0.f, 0.f, 0.f, 0.f};

    const ushort* abase = xg + (size_t)(strip0 * 16 + m) * 64 + q * 8;

    if (t0 >= 2 && t1 <= 61) {
        #pragma unroll
        for (int j = 0; j < 5; ++j) {
            #pragma unroll
            for (int s = 0; s < 2; ++s) {
                const ushort* ab = abase + (ptrdiff_t)(j - 2) * N_DIM * 64 + s * 32;
                s8v af0 = *(const s8v*)ab;
                s8v af1 = *(const s8v*)(ab + 1024);    // +16 rows
                int sg = j * 2 + s;
                #pragma unroll
                for (int c = 0; c < 4; ++c) {
                    s8v bf = *(const s8v*)&Wl[((sg * 4 + c) * 64 + lane) * 8];
                    acc[0][c] = __builtin_amdgcn_mfma_f32_16x16x32_bf16(bf, af0, acc[0][c], 0, 0, 0);
                    acc[1][c] = __builtin_amdgcn_mfma_f32_16x16x32_bf16(bf, af1, acc[1][c], 0, 0, 0);
                }
            }
        }
    } else {
        for (int st = 0; st < 2; ++st) {
            int strip = strip0 + st;
            int t = strip / 125;
            int jlo = (t == 0) ? 2 : ((t == 1) ? 1 : 0);
            int jhi = (t == 63) ? 2 : ((t == 62) ? 3 : 4);
            int tap2off = (t == 0) ? 12288 : ((t == 63) ? 16384 : 0);
            const ushort* ab0 = abase + (size_t)st * 1024;
            for (int j = jlo; j <= jhi; ++j) {
                bool usevar = (j == 2) && (tap2off != 0);
                #pragma unroll
                for (int s = 0; s < 2; ++s) {
                    s8v af = *(const s8v*)(ab0 + (ptrdiff_t)(j - 2) * N_DIM * 64 + s * 32);
                    int sg = j * 2 + s;
                    #pragma unroll
                    for (int c = 0; c < 4; ++c) {
                        int fi = ((sg * 4 + c) * 64 + lane) * 8;
                        s8v bf = usevar ? *(const s8v*)(Wf + tap2off + fi)
                                        : *(const s8v*)&Wl[fi];
                        acc[st][c] = __builtin_amdgcn_mfma_f32_16x16x32_bf16(bf, af, acc[st][c], 0, 0, 0);
                    }
                }
            }
        }
    }

    float ps[16], pq[16];
    #pragma unroll
    for (int i = 0; i < 16; ++i) { ps[i] = 0.f; pq[i] = 0.f; }
    #pragma unroll
    for (int st = 0; st < 2; ++st) {
        int strip = strip0 + st;
        int t = strip / 125;
        int sloc = strip - t * 125;
        int row0 = strip * 16;
        int bcase = (t == 0) ? 0 : ((t == 63) ? 2 : 1);
        float av = a_arr[sloc * 16 + m];
        #pragma unroll
        for (int c = 0; c < 4; ++c) {
            float4 u4 = *(const float4*)&uvec[bcase * 64 + c * 16 + q * 4];
            float4 v4 = *(const float4*)&vvec[bcase * 64 + c * 16 + q * 4];
            float4 r;
            r.x = acc[st][c][0] + av * u4.x + v4.x;
            r.y = acc[st][c][1] + av * u4.y + v4.y;
            r.z = acc[st][c][2] + av * u4.z + v4.z;
            r.w = acc[st][c][3] + av * u4.w + v4.w;
            *(float4*)&out[(size_t)(row0 + m) * 64 + c * 16 + q * 4] = r;
            ps[c * 4 + 0] += r.x; ps[c * 4 + 1] += r.y; ps[c * 4 + 2] += r.z; ps[c * 4 + 3] += r.w;
            pq[c * 4 + 0] += r.x * r.x; pq[c * 4 + 1] += r.y * r.y;
            pq[c * 4 + 2] += r.z * r.z; pq[c * 4 + 3] += r.w * r.w;
        }
    }
    #pragma unroll
    for (int d = 1; d <= 8; d <<= 1) {
        #pragma unroll
        for (int i = 0; i < 16; ++i) {
            ps[i] += __shfl_xor(ps[i], d);
            pq[i] += __shfl_xor(pq[i], d);
        }
    }
    __syncthreads();                 // Wl dead; reuse as sb
    float* sb = (float*)Wl;
    if (tid < 128) sb[tid] = 0.f;
    __syncthreads();
    if (m == 0) {
        #pragma unroll
        for (int i = 0; i < 16; ++i) {
            int ch = (i >> 2) * 16 + q * 4 + (i & 3);
            atomicAdd(&sb[ch], ps[i]);
            atomicAdd(&sb[64 + ch], pq[i]);
        }
    }
    __syncthreads();
    if (tid < 128) atomicAdd(&bnstats[tid], sb[tid]);
}

// ---------------- BN + ReLU, in place; 8000 blocks cover exactly ----------------
__global__ __launch_bounds__(256) void k_bn(float* __restrict__ io,
                                            const float* __restrict__ bnstats,
                                            const float* __restrict__ gamma,
                                            const float* __restrict__ beta) {
    __shared__ float sscale[64], sshift[64];
    int tid = threadIdx.x;
    if (tid < 64) {
        float m = bnstats[tid] * (1.0f / ROWS);
        float v = bnstats[64 + tid] * (1.0f / ROWS) - m * m;
        float sc = gamma[tid] * rsqrtf(v + BN_EPS);
        sscale[tid] = sc;
        sshift[tid] = beta[tid] - m * sc;
    }
    __syncthreads();
    int i4 = blockIdx.x * 256 + tid;     // < 2,048,000 exactly
    float4 v = *(const float4*)(io + (size_t)i4 * 4);
    int c = (i4 * 4) & 63;
    v.x = fmaxf(v.x * sscale[c + 0] + sshift[c + 0], 0.f);
    v.y = fmaxf(v.y * sscale[c + 1] + sshift[c + 1], 0.f);
    v.z = fmaxf(v.z * sscale[c + 2] + sshift[c + 2], 0.f);
    v.w = fmaxf(v.w * sscale[c + 3] + sshift[c + 3], 0.f);
    *(float4*)(io + (size_t)i4 * 4) = v;
}

extern "C" void kernel_launch(void* const* d_in, const int* in_sizes, int n_in,
                              void* d_out, int out_size, void* d_ws, size_t ws_size,
                              hipStream_t stream) {
    const float* x   = (const float*)d_in[0];
    const int*   ei  = (const int*)d_in[1];
    const float* c1w = (const float*)d_in[2];
    const float* c1b = (const float*)d_in[3];
    const float* gw  = (const float*)d_in[4];
    const float* gb  = (const float*)d_in[5];
    const float* c2w = (const float*)d_in[6];
    const float* c2b = (const float*)d_in[7];
    const float* bng = (const float*)d_in[8];
    const float* bnb = (const float*)d_in[9];
    float* out = (float*)d_out;

    // workspace layout
    ushort* xg   = (ushort*)d_ws;                 // ROWS*64 bf16 = 16.4 MB
    ushort* W12f = xg + (size_t)ROWS * 64;        // 28672 (20480 main + 2x4096 variants)
    float*  fb   = (float*)(W12f + 28672);
    float*  Wc1     = fb;                         // 12288
    float*  uvec    = Wc1 + 12288;                // 192
    float*  vvec    = uvec + 192;                 // 192
    float*  bucg    = vvec + 192;                 // 64
    float*  a_arr   = bucg + 64;                  // 2000
    float*  dinv    = a_arr + 2000;               // 2000
    float*  bnstats = dinv + 2000;                // 128
    int*    degi    = (int*)(bnstats + 128);      // 2000
    int*    offs    = degi + 2000;                // 2001
    int*    cursor  = offs + 2001;                // 2000
    int*    iend    = cursor + 2000;
    int2*   edat    = (int2*)((char*)iend + (((size_t)iend) % 8 ? 4 : 0)); // 34000 int2

    hipMemsetAsync(degi, 0, sizeof(int) * N_DIM, stream);

    k_pre1<<<174, 256, 0, stream>>>(ei, c1w, gw, c1b, degi, Wc1, bucg);
    k_pre23<<<30, 1024, 0, stream>>>(degi, Wc1, c2w, gb, c2b, bucg,
                                     dinv, offs, cursor, edat, a_arr, bnstats,
                                     W12f, uvec, vvec);
    k_fill<<<125, 256, 0, stream>>>(ei, offs, dinv, cursor, edat, a_arr);

    // stage 1: Agg(x) -> xg bf16
    k_gather<<<ROWS / 4, 256, 0, stream>>>(x, offs, edat, xg);
    // stage 2: composed K=5 conv + rank-1 bias + BN stats
    k_conv<<<1000, 256, 0, stream>>>(xg, W12f, uvec, vvec, a_arr, out, bnstats);
    // stage 3: BN + ReLU in place
    k_bn<<<8000, 256, 0, stream>>>(out, bnstats, bng, bnb);
}